// Round 14
// baseline (300.110 us; speedup 1.0000x reference)
//
#include <hip/hip_runtime.h>

#define NB 256
#define NT 512
#define NI 64
#define NH 256
#define NO 16

typedef __attribute__((ext_vector_type(8))) short short8;
typedef __attribute__((ext_vector_type(8))) __bf16 bf16x8;
typedef __attribute__((ext_vector_type(2))) float f32x2;
typedef __attribute__((ext_vector_type(4))) float f32x4;
typedef __attribute__((ext_vector_type(4))) int int4v;
typedef __attribute__((ext_vector_type(8))) int int8v;

__device__ __forceinline__ unsigned short f2bf(float f) {
  unsigned u = __builtin_bit_cast(unsigned, f);
  u += 0x7fffu + ((u >> 16) & 1u);          // round-to-nearest-even
  return (unsigned short)(u >> 16);
}

__device__ __forceinline__ f32x4 mfma16(short8 a, short8 b, f32x4 c) {
  return __builtin_amdgcn_mfma_f32_16x16x32_bf16(
      __builtin_bit_cast(bf16x8, a), __builtin_bit_cast(bf16x8, b), c, 0, 0, 0);
}

// MX fp4 K=128 MFMA; scales pinned to 1.0; cbsz=4/blgp=4 -> E2M1 both sides.
// HW reads only v[0:3] of each 8-reg tuple; we keep ALL 8 regs live by
// packing two k-chunks per tuple ([c0|c1] / [c1|c0]) — no dead halves.
__device__ __forceinline__ f32x4 mfma_fp4(int8v a, int8v b, f32x4 c) {
  return __builtin_amdgcn_mfma_scale_f32_16x16x128_f8f6f4(
      a, b, c, 4, 4, 0, 0x7f7f7f7f, 0, 0x7f7f7f7f);
}

// nearest e2m1 code, signed (preamble/W use)
__device__ __forceinline__ int fp4s(float v) {
  const float m = fabsf(v);
  int c;
  if (m < 1.75f)      c = (int)(m * 2.f + 0.5f);
  else if (m < 2.5f)  c = 4;
  else if (m < 3.5f)  c = 5;
  else if (m < 5.0f)  c = 6;
  else                c = 7;
  return c | (v < 0.f ? 8 : 0);
}

// nearest e2m1 code for v in [0,6] (h post-clamp: sign-free, branchless)
__device__ __forceinline__ int fp4u(float v) {
  int c = (int)fminf(v * 2.f + 0.5f, 3.f);
  c = (v >= 1.75f) ? 4 : c;
  c = (v >= 2.5f)  ? 5 : c;
  c = (v >= 3.5f)  ? 6 : c;
  c = (v >= 5.0f)  ? 7 : c;
  return c;
}

__device__ __forceinline__ short8 pack8v(f32x4 lo, f32x4 hi) {
  short8 r;
#pragma unroll
  for (int i = 0; i < 4; ++i) {
    r[i]     = (short)f2bf(lo[i]);
    r[i + 4] = (short)f2bf(hi[i]);
  }
  return r;
}

__device__ __forceinline__ short8 pack8(const float* __restrict__ p) {
  return pack8v(*reinterpret_cast<const f32x4*>(p),
                *reinterpret_cast<const f32x4*>(p + 4));
}

// LDS-only barrier: drain DS ops, sync; global stores/loads stay in flight.
__device__ __forceinline__ void step_barrier() {
  asm volatile("s_waitcnt lgkmcnt(0)" ::: "memory");
  __builtin_amdgcn_s_barrier();
  asm volatile("" ::: "memory");
}

// One block per batch. 512 threads = 8 waves (2/SIMD).  [R6/R13 structure]
// h2h via MX-fp4 K=128: A = broadcast h (fp4, 128B nibble buffer), B =
// per-row-scaled Wh (fp4). Tuple-pair trick keeps all MFMA operand regs
// live. 4 independent MFMAs/wave/step -> ~178cy/SIMD pipe floor.
// xi per window in REGISTERS (bias folded at write); persistent Wo frags.
__global__ __launch_bounds__(512, 2)
void rnn_fused(const float* __restrict__ x,  const float* __restrict__ Wi,
               const float* __restrict__ bi, const float* __restrict__ Wh,
               const float* __restrict__ bh, const float* __restrict__ Wo,
               const float* __restrict__ bo, const float* __restrict__ h0,
               float* __restrict__ dout)
{
  const int b   = blockIdx.x;
  const int tid = threadIdx.x;
  const int w   = tid >> 6;   // wave 0..7
  const int l   = tid & 63;   // lane
  const int lg  = l >> 4;     // 16-lane group
  const int ll  = l & 15;     // index within tile

  __shared__ __align__(16) unsigned char  hq4[2][128];      // fp4 h nibbles
  __shared__ __align__(16) unsigned short rnnwin[16 * NH];  // 8 KB bf16 ring
  __shared__ __align__(16) float          xi_lds[NH][20];   // [j][t(16)+pad4]

  float* outp = dout;                              // [B,T,O]
  float* hidp = dout + (size_t)NB * NT * NO;       // [B,H]
  float* rnnp = hidp + (size_t)NB * NH;            // [B,T,H]

  const f32x4 cz = {0.f, 0.f, 0.f, 0.f};

  // ---- Wh -> fp4 B-fragments, per-row scale 6/m; row j = w*32 + jt*16 + ll,
  //      k = kc*128 + lg*32 + e (nibble e&1 of byte kc*64+lg*16+e/2).
  //      Tuples: wq4[jt][0]=[c0|c1], wq4[jt][1]=[c1|c0] — all regs live. ----
  int8v wq4[2][2];
  float dq[2];
#pragma unroll
  for (int jt = 0; jt < 2; ++jt) {
    const int j = w * 32 + jt * 16 + ll;
    const float* wr = Wh + (size_t)j * NH;
    float m = 0.f;
#pragma unroll
    for (int kc = 0; kc < 2; ++kc)
#pragma unroll
      for (int e4 = 0; e4 < 8; ++e4) {
        f32x4 v = *reinterpret_cast<const f32x4*>(wr + kc * 128 + lg * 32 + e4 * 4);
#pragma unroll
        for (int i = 0; i < 4; ++i) m = fmaxf(m, fabsf(v[i]));
      }
    m = fmaxf(m, __shfl_xor(m, 16));
    m = fmaxf(m, __shfl_xor(m, 32));
    const float s = (m > 0.f) ? 6.f / m : 0.f;
    dq[jt] = m * (1.f / 36.f);
    unsigned u[8] = {0u, 0u, 0u, 0u, 0u, 0u, 0u, 0u};
#pragma unroll
    for (int kc = 0; kc < 2; ++kc)
#pragma unroll
      for (int e = 0; e < 32; ++e) {
        const int code = fp4s(wr[kc * 128 + lg * 32 + e] * s);
        u[kc * 4 + (e >> 3)] |= ((unsigned)code) << (4 * (e & 7));
      }
    int8v t0 = {(int)u[0], (int)u[1], (int)u[2], (int)u[3],
                (int)u[4], (int)u[5], (int)u[6], (int)u[7]};
    int8v t1 = {(int)u[4], (int)u[5], (int)u[6], (int)u[7],
                (int)u[0], (int)u[1], (int)u[2], (int)u[3]};
    wq4[jt][0] = t0;
    wq4[jt][1] = t1;
  }

  // ---- bf16 i2h weights + PERSISTENT out-proj weights (R6 lesson) ----
  short8 wif[2][2];
  float bregW[2];
#pragma unroll
  for (int jt = 0; jt < 2; ++jt) {
    const int j = w * 32 + jt * 16 + ll;
#pragma unroll
    for (int kx = 0; kx < 2; ++kx)
      wif[jt][kx] = pack8(Wi + (size_t)j * NI + kx * 32 + lg * 8);
    bregW[jt] = bi[j] + bh[j];            // bias folded at xi write
  }
  short8 woA[8];
#pragma unroll
  for (int kt = 0; kt < 8; ++kt)
    woA[kt] = pack8(Wo + (size_t)ll * NH + kt * 32 + lg * 8);
  const float bout = bo[ll];

  float h_reg0 = h0[w * 32 + ll];
  float h_reg1 = h0[w * 32 + 16 + ll];

  // writer lanes (lg<2): own j = w*32 + lg*16 + ll
  const int  jw     = w * 32 + lg * 16 + ll;
  const bool wr_act = (lg < 2);

  // ---- init hq4[0] from h0 (nibble-packed) ----
  if (tid < 128) {
    const int q0 = fp4s(fminf(fmaxf(h0[2 * tid],     -1.f), 1.f) * 6.f);
    const int q1 = fp4s(fminf(fmaxf(h0[2 * tid + 1], -1.f), 1.f) * 6.f);
    hq4[0][tid] = (unsigned char)(q0 | (q1 << 4));
  }

  // ---- x prefetch (one window ahead): lane row ll, 16 f32 ----
  const float* xrow = x + (size_t)b * NT * NI + (size_t)ll * NI + lg * 8;
  f32x4 xpre[4];
  xpre[0] = *reinterpret_cast<const f32x4*>(xrow);
  xpre[1] = *reinterpret_cast<const f32x4*>(xrow + 4);
  xpre[2] = *reinterpret_cast<const f32x4*>(xrow + 32);
  xpre[3] = *reinterpret_cast<const f32x4*>(xrow + 36);

  __syncthreads();

  const int j0 = w * 32 + ll;        // jt=0 row
  const int j1 = w * 32 + 16 + ll;   // jt=1 row

  auto outproj = [&](int tbase) {    // out[tbase-16 .. tbase-1] from rnnwin
    f32x4 oacc = cz;
#pragma unroll
    for (int kt = 0; kt < 8; ++kt) {
      const char* ap = (const char*)rnnwin + ll * 512 +
                       ((kt * 64 + lg * 16) ^ (ll << 4));
      short8 af = *reinterpret_cast<const short8*>(ap);
      oacc = mfma16(af, woA[kt], oacc);
    }
#pragma unroll
    for (int r = 0; r < 4; ++r) {
      const int tp = lg * 4 + r;
      outp[((size_t)b * NT + tbase - 16 + tp) * NO + ll] = oacc[r] + bout;
    }
  };

#define STEP(TT, XIV0, XIV1)                                                   \
  {                                                                            \
    const int t    = (TT);                                                     \
    const int trow = t & 15;                                                   \
    const int p    = t & 1;                                                    \
    const unsigned char* hb = hq4[p];                                          \
    int8v A0, A1;                                                              \
    *(int4v*)&A0       = *(const int4v*)(hb + lg * 16);        /* c0 */        \
    *((int4v*)&A0 + 1) = *(const int4v*)(hb + 64 + lg * 16);   /* c1 live */   \
    *(int4v*)&A1       = *(const int4v*)(hb + 64 + lg * 16);   /* c1 */        \
    *((int4v*)&A1 + 1) = *(const int4v*)(hb + lg * 16);        /* c0 live */   \
    const float hx0 = h_reg0 + (XIV0);   /* xi carries bias */                 \
    const float hx1 = h_reg1 + (XIV1);                                         \
    f32x4 a00 = mfma_fp4(A0, wq4[0][0], cz);                                   \
    f32x4 a10 = mfma_fp4(A0, wq4[1][0], cz);                                   \
    f32x4 a01 = mfma_fp4(A1, wq4[0][1], cz);                                   \
    f32x4 a11 = mfma_fp4(A1, wq4[1][1], cz);                                   \
    const float s0 = a00[0] + a01[0];                                          \
    const float s1 = a10[0] + a11[0];                                          \
    const float a0 = __builtin_amdgcn_fmed3f(fmaf(s0, dq[0], hx0), 0.f, 1.f);  \
    const float a1 = __builtin_amdgcn_fmed3f(fmaf(s1, dq[1], hx1), 0.f, 1.f);  \
    h_reg0 = a0; h_reg1 = a1;                                                  \
    const float aw = lg ? a1 : a0;                                             \
    const int   qn = fp4u(aw * 6.f);                                           \
    const int   qp = __shfl_xor(qn, 1);                                        \
    if (wr_act) {                                                              \
      if (!(ll & 1))                                                           \
        hq4[p ^ 1][jw >> 1] = (unsigned char)(qn | (qp << 4));                 \
      const int byte = trow * 512 + ((2 * jw) ^ (trow << 4));                  \
      rnnwin[byte >> 1] = f2bf(aw);                                            \
      rnnp[((size_t)b * NT + t) * NH + jw] = aw;                               \
    }                                                                          \
    step_barrier();                                                            \
  }

#pragma unroll 1
  for (int t0 = 0; t0 < NT; t0 += 16) {
    // ---- window boundary: rotating out-proj + i2h GEMM + x prefetch ----
    if (t0 > 0 && w == (((t0 >> 4) - 1) & 7)) outproj(t0);
    {
      short8 xf0 = pack8v(xpre[0], xpre[1]);
      short8 xf1 = pack8v(xpre[2], xpre[3]);
#pragma unroll
      for (int jt = 0; jt < 2; ++jt) {
        f32x4 acc = mfma16(xf0, wif[jt][0], cz);
        acc = mfma16(xf1, wif[jt][1], acc);
        const int j = w * 32 + jt * 16 + ll;
        f32x4 xo;
#pragma unroll
        for (int r = 0; r < 4; ++r) xo[r] = acc[r] + bregW[jt];
        *(f32x4*)&xi_lds[j][lg * 4] = xo;   // rows r -> t = lg*4 + r
      }
    }
    if (t0 + 16 < NT) {
      const float* xp = x + (size_t)b * NT * NI + (size_t)(t0 + 16 + ll) * NI + lg * 8;
      xpre[0] = *reinterpret_cast<const f32x4*>(xp);
      xpre[1] = *reinterpret_cast<const f32x4*>(xp + 4);
      xpre[2] = *reinterpret_cast<const f32x4*>(xp + 32);
      xpre[3] = *reinterpret_cast<const f32x4*>(xp + 36);
    }
    step_barrier();

    // ---- whole window's xi into registers (statically indexed below) ----
    f32x4 xqA[4], xqB[4];
#pragma unroll
    for (int q = 0; q < 4; ++q) {
      xqA[q] = *(const f32x4*)&xi_lds[j0][q * 4];
      xqB[q] = *(const f32x4*)&xi_lds[j1][q * 4];
    }

    STEP(t0 + 0,  xqA[0][0], xqB[0][0]) STEP(t0 + 1,  xqA[0][1], xqB[0][1])
    STEP(t0 + 2,  xqA[0][2], xqB[0][2]) STEP(t0 + 3,  xqA[0][3], xqB[0][3])
    STEP(t0 + 4,  xqA[1][0], xqB[1][0]) STEP(t0 + 5,  xqA[1][1], xqB[1][1])
    STEP(t0 + 6,  xqA[1][2], xqB[1][2]) STEP(t0 + 7,  xqA[1][3], xqB[1][3])
    STEP(t0 + 8,  xqA[2][0], xqB[2][0]) STEP(t0 + 9,  xqA[2][1], xqB[2][1])
    STEP(t0 + 10, xqA[2][2], xqB[2][2]) STEP(t0 + 11, xqA[2][3], xqB[2][3])
    STEP(t0 + 12, xqA[3][0], xqB[3][0]) STEP(t0 + 13, xqA[3][1], xqB[3][1])
    STEP(t0 + 14, xqA[3][2], xqB[3][2]) STEP(t0 + 15, xqA[3][3], xqB[3][3])
  }
#undef STEP

  // ---- epilogue: final window out-proj (rotation slot 31&7 = 7) + hidden ----
  if (w == 7) outproj(NT);
  if (wr_act) {
    const float aw = lg ? h_reg1 : h_reg0;
    hidp[(size_t)b * NH + jw] = aw;
  }
}

extern "C" void kernel_launch(void* const* d_in, const int* in_sizes, int n_in,
                              void* d_out, int out_size, void* d_ws, size_t ws_size,
                              hipStream_t stream) {
  const float* x  = (const float*)d_in[0];
  const float* Wi = (const float*)d_in[1];
  const float* bi = (const float*)d_in[2];
  const float* Wh = (const float*)d_in[3];
  const float* bh = (const float*)d_in[4];
  const float* Wo = (const float*)d_in[5];
  const float* bo = (const float*)d_in[6];
  const float* h0 = (const float*)d_in[7];
  rnn_fused<<<dim3(NB), dim3(512), 0, stream>>>(x, Wi, bi, Wh, bh, Wo, bo, h0,
                                                (float*)d_out);
}